// Round 22
// baseline (101.994 us; speedup 1.0000x reference)
//
#include <hip/hip_runtime.h>

#define NH   12
#define HD   64
#define H    768
#define B_   2
#define S_   2048
#define MTOT (B_*S_)   // 4096

typedef short bf16x8 __attribute__((ext_vector_type(8)));
typedef float f32x4  __attribute__((ext_vector_type(4)));
typedef float f32x16 __attribute__((ext_vector_type(16)));
typedef unsigned uint32x2 __attribute__((ext_vector_type(2)));

#define MFMA16(a,b,c) __builtin_amdgcn_mfma_f32_16x16x32_bf16((a),(b),(c),0,0,0)
#define MFMA32(a,b,c) __builtin_amdgcn_mfma_f32_32x32x16_bf16((a),(b),(c),0,0,0)
#define GLL16(g,l) __builtin_amdgcn_global_load_lds( \
    (const __attribute__((address_space(1))) void*)(g), \
    (__attribute__((address_space(3))) void*)(l), 16, 0, 0)
#define EXP2F(x) __builtin_amdgcn_exp2f(x)
#define SCHEDB() __builtin_amdgcn_sched_barrier(0)
#define SBAR()   __builtin_amdgcn_s_barrier()

// permlane32_swap semantics (LLVM): result = {new_a, new_b} with
//   new_a[32:63] = b_old[0:31], new_a[0:31] = a_old[0:31]
//   new_b[0:31]  = a_old[32:63], new_b[32:63] = b_old[32:63]
#if __has_builtin(__builtin_amdgcn_permlane32_swap)
__device__ __forceinline__ uint32x2 plswap(unsigned a, unsigned b){
    return __builtin_amdgcn_permlane32_swap(a, b, false, false);
}
#else
__device__ __forceinline__ uint32x2 plswap(unsigned a, unsigned b){
    const int hi = (threadIdx.x & 63) >> 5;
    const unsigned pa = (unsigned)__shfl_xor((int)a, 32);
    const unsigned pb = (unsigned)__shfl_xor((int)b, 32);
    uint32x2 r;
    r.x = hi ? pb : a;    // new_a
    r.y = hi ? b  : pa;   // new_b
    return r;
}
#endif

// cross-half reduce: commutative combine is convention-safe.
__device__ __forceinline__ float cross32_max(float x){
    uint32x2 r = plswap(__float_as_uint(x), __float_as_uint(x));
    return fmaxf(__uint_as_float(r.x), __uint_as_float(r.y));
}
__device__ __forceinline__ float cross32_add(float x){
    uint32x2 r = plswap(__float_as_uint(x), __float_as_uint(x));
    return __uint_as_float(r.x) + __uint_as_float(r.y);
}

__device__ __forceinline__ unsigned short f2bf(float x){
    union { float f; unsigned u; } c; c.f = x;
    unsigned r = (c.u + 0x7FFFu + ((c.u >> 16) & 1u)) >> 16;   // RNE
    return (unsigned short)r;
}

// ---------------------------------------------------------------------------
// Flat vectorized pre-pass (G13): five contiguous row-major regions, each a
// pure fp32 -> bf16 cast, processed as float4 -> ushort4 (fully coalesced).
// ---------------------------------------------------------------------------
#define XB 3072   // MTOT*H/4/256
#define WB 576    // 768*H/4/256
__global__ __launch_bounds__(256) void prep(
    const float* __restrict__ hs,
    const float* __restrict__ wq, const float* __restrict__ wk,
    const float* __restrict__ wv, const float* __restrict__ wo,
    unsigned short* __restrict__ Xh, unsigned short* __restrict__ Wqkv,
    unsigned short* __restrict__ Wo_)
{
    const int bid = blockIdx.x;
    const float* src;
    unsigned short* dst;
    int ib;
    if (bid < XB){
        src = hs; dst = Xh; ib = bid;
    } else {
        const int w = (bid - XB) / WB;
        ib = (bid - XB) - w*WB;
        src = (w==0)?wq:(w==1)?wk:(w==2)?wv:wo;
        dst = (w < 3) ? (Wqkv + (size_t)w*768*H) : Wo_;
    }
    const size_t i = (size_t)ib*256 + threadIdx.x;
    const float4 v = ((const float4*)src)[i];
    ushort4 o;
    o.x = f2bf(v.x); o.y = f2bf(v.y); o.z = f2bf(v.z); o.w = f2bf(v.w);
    ((ushort4*)dst)[i] = o;
}

// ---------------------------------------------------------------------------
// GEMM, 64x128 tile, 4 waves 2x2 (r16 form, measured best). 1-term bf16,
// K=768, BK=32, double-buffered, counted vmcnt(3) + builtin s_barrier.
// MODE 1 (QKV): Q/K stored NATURAL [b][s][H]; V scattered to V^T.
// MODE 0 (out-proj): fp32 store + bias.
// ---------------------------------------------------------------------------
template<int MODE>
__global__ __launch_bounds__(256) void gemm_bf16(
    const unsigned short* __restrict__ A, const unsigned short* __restrict__ Bm,
    const float* __restrict__ b0, const float* __restrict__ b1,
    const float* __restrict__ b2,
    float* __restrict__ out,
    unsigned short* __restrict__ Qh, unsigned short* __restrict__ Kh,
    unsigned short* __restrict__ Vh)
{
    constexpr int NIT = H/32;   // 24 K-iterations

    __shared__ unsigned short As[2][64*32];
    __shared__ unsigned short Bs[2][128*32];
    const int tid = threadIdx.x, lane = tid & 63, wave = tid >> 6;
    const int m0 = blockIdx.x*64, n0 = blockIdx.y*128;
    const int wr = wave >> 1, wc = wave & 1;
    const int frow = lane & 15, foct = lane >> 4;
    const int arow = lane >> 2;
    const int achk = ((lane & 3) ^ (arow & 3)) * 8;
    const int fswz = (foct ^ (frow & 3)) * 8;

    auto STAGE = [&](int bufi, int kp){
        {
            const int r0 = wave*16;
            GLL16(A + (size_t)(m0 + r0 + arow)*H + kp + achk, &As[bufi][r0*32]);
        }
        #pragma unroll
        for (int i = 0; i < 2; ++i){
            const int r0 = (wave*2 + i)*16;
            GLL16(Bm + (size_t)(n0 + r0 + arow)*H + kp + achk, &Bs[bufi][r0*32]);
        }
    };

    STAGE(0, 0);
    STAGE(1, 32);

    f32x4 acc[2][4] = {};

    for (int it = 0; it < NIT; ++it){
        const int cur = it & 1;
        if (it + 1 < NIT) asm volatile("s_waitcnt vmcnt(3)");
        else              asm volatile("s_waitcnt vmcnt(0)");
        SCHEDB();
        SBAR();
        SCHEDB();           // buf[cur] loads visible to all waves

        bf16x8 af[2], bfv[4];
        #pragma unroll
        for (int i = 0; i < 2; ++i)
            af[i]  = *(const bf16x8*)&As[cur][(wr*32 + 16*i + frow)*32 + fswz];
        #pragma unroll
        for (int j = 0; j < 4; ++j)
            bfv[j] = *(const bf16x8*)&Bs[cur][(wc*64 + 16*j + frow)*32 + fswz];
        #pragma unroll
        for (int i = 0; i < 2; ++i)
            #pragma unroll
            for (int j = 0; j < 4; ++j)
                acc[i][j] = MFMA16(af[i], bfv[j], acc[i][j]);

        SCHEDB();
        SBAR();             // all waves done reading buf[cur]
        SCHEDB();
        if (it + 2 < NIT) STAGE(cur, (it + 2)*32);
    }

    if (MODE == 0){
        #pragma unroll
        for (int i = 0; i < 2; ++i){
            const int m = m0 + wr*32 + 16*i + 4*foct;
            #pragma unroll
            for (int j = 0; j < 4; ++j){
                const int n = n0 + wc*64 + 16*j + frow;
                const float bb = b0[n];
                #pragma unroll
                for (int r = 0; r < 4; ++r)
                    out[(size_t)(m + r)*H + n] = acc[i][j][r] + bb;
            }
        }
    } else {
        const int sect = n0 / 768;                 // 0=Q 1=K 2=V (block-uniform)
        const float* bias = (sect==0) ? b0 : (sect==1) ? b1 : b2;
        // Q scale folds 1/sqrt(HD) AND 1/ln2 (softmax runs in exp2 space)
        const float qs = (sect==0) ? 0.125f*1.44269504f : 1.0f;
        unsigned short* Ph = (sect==0) ? Qh : Kh;
        #pragma unroll
        for (int i = 0; i < 2; ++i){
            const int m  = m0 + wr*32 + 16*i + 4*foct;
            const int bb = m >> 11, ss = m & (S_-1);
            #pragma unroll
            for (int j = 0; j < 4; ++j){
                const int nn = (n0 - sect*768) + wc*64 + 16*j + frow;
                const float bv_ = bias[nn];
                unsigned short hi[4];
                #pragma unroll
                for (int r = 0; r < 4; ++r)
                    hi[r] = f2bf((acc[i][j][r] + bv_) * qs);
                if (sect < 2){                     // NATURAL [b][s][H] (n=h*64+d)
                    #pragma unroll
                    for (int r = 0; r < 4; ++r)
                        Ph[((size_t)bb*S_ + ss + r)*H + nn] = hi[r];
                } else {                           // V^T [b][h][d][s]
                    const int hh = nn >> 6, dd = nn & 63;
                    const size_t a = ((size_t)(bb*NH + hh)*HD + dd)*S_ + ss;
                    ushort4 ph; ph.x=hi[0]; ph.y=hi[1]; ph.z=hi[2]; ph.w=hi[3];
                    *(ushort4*)&Vh[a] = ph;
                }
            }
        }
    }
}

// ---------------------------------------------------------------------------
// Flash attention, fully fused (r21 structure) MINUS s_setprio: m190 showed
// setprio costs ~1.5% in barrier-locked lockstep structures (ours: all 4
// waves share every barrier) - it starves the staging waves' GLL issue while
// boosting a wave that stalls at the same barrier anyway.
// ---------------------------------------------------------------------------
__global__ __launch_bounds__(256, 3) void attn_mfma(
    const unsigned short* __restrict__ Qh, const unsigned short* __restrict__ Kh,
    const unsigned short* __restrict__ Vh,
    const int* __restrict__ mask, unsigned short* __restrict__ Cs)
{
    __shared__ unsigned short Ksh[2][64*64];
    __shared__ unsigned short Vsh[2][64*64];

    const int tid = threadIdx.x, lane = tid & 63, wave = tid >> 6;  // 4 waves
    const int q0 = blockIdx.x*64, h = blockIdx.y, b = blockIdx.z;
    const int qb = wave & 1, kp2 = wave >> 1;     // q-block, k-parity
    const int l31 = lane & 31, hi = lane >> 5, l7 = lane & 7;
    const size_t kbase = ((size_t)b*S_)*H + h*HD; // K rows [s][H] + head slice
    const size_t vbase = (size_t)(b*NH + h)*HD;   // V rows [d][s]
    const int srow = lane >> 3;                   // 8 rows per GLL (128B slices)
    const int schk = ((lane & 7) ^ srow) * 8;     // pre-swizzled source chunk

    // stage tile te -> buf0 (K,V) and te+1 -> buf1; 8 GLLs per wave
    auto STAGE2 = [&](int te){
        if (wave == 0){
            #pragma unroll
            for (int i = 0; i < 8; ++i){
                const int r0 = i*8, row = r0 + srow;
                GLL16(Kh + kbase + (size_t)(te*64 + row)*H + schk, &Ksh[0][r0*64]);
            }
        } else if (wave == 1){
            #pragma unroll
            for (int i = 0; i < 8; ++i){
                const int r0 = i*8, row = r0 + srow;
                GLL16(Vh + (vbase + row)*S_ + (size_t)te*64 + schk, &Vsh[0][r0*64]);
            }
        } else if (wave == 2){
            #pragma unroll
            for (int i = 0; i < 8; ++i){
                const int r0 = i*8, row = r0 + srow;
                GLL16(Kh + kbase + (size_t)((te+1)*64 + row)*H + schk, &Ksh[1][r0*64]);
            }
        } else {
            #pragma unroll
            for (int i = 0; i < 8; ++i){
                const int r0 = i*8, row = r0 + srow;
                GLL16(Vh + (vbase + row)*S_ + (size_t)(te+1)*64 + schk, &Vsh[1][r0*64]);
            }
        }
    };

    // ---- mask bits: lane L holds keys L*32..L*32+31 (batch b) ----
    unsigned mbits = 0;
    {
        const int* mp = mask + (size_t)b*S_ + lane*32;
        #pragma unroll
        for (int j = 0; j < 32; ++j) mbits |= (mp[j] ? 1u : 0u) << j;
    }

    // ---- Q fragments (B-op: col=l31 -> q row q0+qb*32+l31, k=hi*8+e) ----
    bf16x8 qf[4];
    {
        const size_t qr = ((size_t)b*S_ + q0 + qb*32 + l31)*H + h*HD;
        #pragma unroll
        for (int ds = 0; ds < 4; ++ds)
            qf[ds] = *(const bf16x8*)&Qh[qr + ds*16 + hi*8];
    }

    STAGE2(0);

    float mR = -1e30f, lR = 0.f;
    f32x16 o0 = {}, o1 = {};

    for (int tt = 0; tt < 16; ++tt){
        const int t = 2*tt + kp2;                 // this wave's tile
        asm volatile("s_waitcnt vmcnt(0)");
        SCHEDB();
        SBAR();
        SCHEDB();           // both parity buffers for this round visible

        // ---- S^T = K Q'^T : 8 mfma, 2 indep chains (scores in log2 units) ----
        f32x16 s0 = {}, s1 = {};
        #pragma unroll
        for (int ds = 0; ds < 4; ++ds){
            const int c0 = ((2*ds + hi) ^ l7)*8;
            const bf16x8 kh0 = *(const bf16x8*)&Ksh[kp2][l31*64 + c0];
            const bf16x8 kh1 = *(const bf16x8*)&Ksh[kp2][(32+l31)*64 + c0];
            s0 = MFMA32(kh0, qf[ds], s0);
            s1 = MFMA32(kh1, qf[ds], s1);
        }

        // ---- mask via preloaded bits (no memory ops) ----
        {
            const unsigned bm_lo = (unsigned)__shfl((int)mbits, 2*t);
            const unsigned bm_hi = (unsigned)__shfl((int)mbits, 2*t + 1);
            const unsigned long long mb = ((unsigned long long)bm_hi << 32) | bm_lo;
            if (~mb){
                #pragma unroll
                for (int r = 0; r < 16; ++r){
                    const int key = (r&3) + 8*(r>>2) + 4*hi;
                    if (!((mb >> key) & 1))      s0[r] = -1e9f;
                    if (!((mb >> (key+32)) & 1)) s1[r] = -1e9f;
                }
            }
        }

        // ---- online softmax (lane-local + permlane cross-half) ----
        float vmax = -1e30f;
        #pragma unroll
        for (int r = 0; r < 16; ++r) vmax = fmaxf(vmax, fmaxf(s0[r], s1[r]));
        vmax = cross32_max(vmax);
        if (!__all(vmax <= mR + 11.5f)){          // T13 defer (log2 units)
            const float mnew = fmaxf(mR, vmax);
            const float sc = EXP2F(mR - mnew);
            mR = mnew; lR *= sc;
            #pragma unroll
            for (int r = 0; r < 16; ++r){ o0[r] *= sc; o1[r] *= sc; }
        }
        float ps = 0.f;
        #pragma unroll
        for (int r = 0; r < 16; ++r){
            s0[r] = EXP2F(s0[r] - mR);
            s1[r] = EXP2F(s1[r] - mR);
            ps += s0[r] + s1[r];
        }
        ps = cross32_add(ps);
        lR += ps;

        // ---- pack P^T to bf16 B-frags (cvt_pk + permlane32_swap builtin) ----
        bf16x8 pf[4];
        #pragma unroll
        for (int s = 0; s < 4; ++s){
            const f32x16& pv = (s < 2) ? s0 : s1;
            const int rb = (s & 1)*8;
            unsigned w0, w1, w2, w3;
            asm("v_cvt_pk_bf16_f32 %0, %1, %2" : "=v"(w0) : "v"(pv[rb+0]), "v"(pv[rb+1]));
            asm("v_cvt_pk_bf16_f32 %0, %1, %2" : "=v"(w1) : "v"(pv[rb+2]), "v"(pv[rb+3]));
            asm("v_cvt_pk_bf16_f32 %0, %1, %2" : "=v"(w2) : "v"(pv[rb+4]), "v"(pv[rb+5]));
            asm("v_cvt_pk_bf16_f32 %0, %1, %2" : "=v"(w3) : "v"(pv[rb+6]), "v"(pv[rb+7]));
            const uint32x2 r02 = plswap(w0, w2);
            const uint32x2 r13 = plswap(w1, w3);
            union { uint4 u; bf16x8 v; } pk;
            pk.u.x = r02.x; pk.u.y = r13.x; pk.u.z = r02.y; pk.u.w = r13.y;
            pf[s] = pk.v;
        }

        // ---- O^T += V^T P^T : 8 mfma, 2 indep chains ----
        #pragma unroll
        for (int s = 0; s < 4; ++s){
            const int c0 = ((2*s + hi) ^ l7)*8;
            const bf16x8 vh0 = *(const bf16x8*)&Vsh[kp2][l31*64 + c0];
            const bf16x8 vh1 = *(const bf16x8*)&Vsh[kp2][(32+l31)*64 + c0];
            o0 = MFMA32(vh0, pf[s], o0);
            o1 = MFMA32(vh1, pf[s], o1);
        }

        SCHEDB();
        SBAR();             // all waves done reading this round's buffers
        SCHEDB();
        if (tt + 1 < 16) STAGE2(2*(tt + 1));      // stage next parity pair
    }

    // ---- epilogue: in-LDS merge of even/odd partials, write bf16 Cs ----
    float* Olds = (float*)&Ksh[0][0];
    float* Mlds = (float*)&Vsh[0][0];
    const int qi = qb*32 + l31;

    if (kp2 == 1){          // odd-parity waves publish partials
        #pragma unroll
        for (int a = 0; a < 4; ++a){
            const int d0 = 8*a + 4*hi;
            f32x4 v0, v1;
            #pragma unroll
            for (int r = 0; r < 4; ++r){ v0[r] = o0[a*4+r]; v1[r] = o1[a*4+r]; }
            *(f32x4*)&Olds[qi*64 + d0]      = v0;
            *(f32x4*)&Olds[qi*64 + 32 + d0] = v1;
        }
        if (hi == 0){
            Mlds[qi*2]     = mR;
            Mlds[qi*2 + 1] = lR;
        }
    }
    __syncthreads();        // full drain: publishes visible to even waves

    if (kp2 == 0){          // even-parity waves merge + write
        const float mo = Mlds[qi*2], lo = Mlds[qi*2 + 1];
        const float mm = fmaxf(mR, mo);
        const float we = EXP2F(mR - mm), wo_ = EXP2F(mo - mm);
        const float inv = 1.0f / (lR*we + lo*wo_);
        const int sg = q0 + qi;
        unsigned short* Crow = Cs + ((size_t)b*S_ + sg)*H + h*HD;
        #pragma unroll
        for (int a = 0; a < 4; ++a){
            const int d0 = 8*a + 4*hi;
            ushort4 u0, u1;
            #pragma unroll
            for (int r = 0; r < 4; ++r){
                const float e0 = (o0[a*4+r]*we + Olds[qi*64 + d0 + r]*wo_)*inv;
                const float e1 = (o1[a*4+r]*we + Olds[qi*64 + 32 + d0 + r]*wo_)*inv;
                ((unsigned short*)&u0)[r] = f2bf(e0);
                ((unsigned short*)&u1)[r] = f2bf(e1);
            }
            *(ushort4*)&Crow[d0]      = u0;
            *(ushort4*)&Crow[32 + d0] = u1;
        }
    }
}

extern "C" void kernel_launch(void* const* d_in, const int* in_sizes, int n_in,
                              void* d_out, int out_size, void* d_ws, size_t ws_size,
                              hipStream_t stream) {
    const float* hs = (const float*)d_in[0];
    const int*  msk = (const int*)  d_in[1];
    const float* wq = (const float*)d_in[2];
    const float* bq = (const float*)d_in[3];
    const float* wk = (const float*)d_in[4];
    const float* bk = (const float*)d_in[5];
    const float* wv = (const float*)d_in[6];
    const float* bv = (const float*)d_in[7];
    const float* wo = (const float*)d_in[8];
    const float* bo = (const float*)d_in[9];
    float* out = (float*)d_out;

    const size_t XH_E   = (size_t)MTOT*H;        // 3.1M shorts
    const size_t WQKV_E = (size_t)2304*H;
    const size_t WO_E   = (size_t)768*H;
    const size_t QKV_E  = (size_t)MTOT*H;        // Q/K natural layout
    const size_t V_E    = (size_t)B_*NH*S_*HD;   // V^T
    const size_t CS_E   = (size_t)MTOT*H;        // 3.1M shorts

    unsigned short* p = (unsigned short*)d_ws;
    unsigned short* Xh   = p; p += XH_E;
    unsigned short* Wqkv = p; p += WQKV_E;
    unsigned short* Wo_  = p; p += WO_E;
    unsigned short* Qh = p; p += QKV_E;
    unsigned short* Kh = p; p += QKV_E;
    unsigned short* Vh = p; p += V_E;
    unsigned short* Cs = p; p += CS_E;

    prep<<<dim3(XB + 4*WB), 256, 0, stream>>>(
        hs, wq, wk, wv, wo, Xh, Wqkv, Wo_);
    gemm_bf16<1><<<dim3(MTOT/64, 2304/128), 256, 0, stream>>>(
        Xh, Wqkv, bq, bk, bv, nullptr, Qh, Kh, Vh);
    attn_mfma<<<dim3(S_/64, NH, B_), 256, 0, stream>>>(
        Qh, Kh, Vh, msk, Cs);
    gemm_bf16<0><<<dim3(MTOT/64, H/128), 256, 0, stream>>>(
        Cs, Wo_, bo, nullptr, nullptr, out,
        nullptr, nullptr, nullptr);
}

// Round 23
// 100.464 us; speedup vs baseline: 1.0152x; 1.0152x over previous
//
#include <hip/hip_runtime.h>

#define NH   12
#define HD   64
#define H    768
#define B_   2
#define S_   2048
#define MTOT (B_*S_)   // 4096

typedef short bf16x8 __attribute__((ext_vector_type(8)));
typedef float f32x4  __attribute__((ext_vector_type(4)));
typedef float f32x16 __attribute__((ext_vector_type(16)));
typedef unsigned uint32x2 __attribute__((ext_vector_type(2)));

#define MFMA16(a,b,c) __builtin_amdgcn_mfma_f32_16x16x32_bf16((a),(b),(c),0,0,0)
#define MFMA32(a,b,c) __builtin_amdgcn_mfma_f32_32x32x16_bf16((a),(b),(c),0,0,0)
#define GLL16(g,l) __builtin_amdgcn_global_load_lds( \
    (const __attribute__((address_space(1))) void*)(g), \
    (__attribute__((address_space(3))) void*)(l), 16, 0, 0)
#define EXP2F(x) __builtin_amdgcn_exp2f(x)
#define SCHEDB() __builtin_amdgcn_sched_barrier(0)
#define SBAR()   __builtin_amdgcn_s_barrier()

// permlane32_swap semantics (LLVM): result = {new_a, new_b} with
//   new_a[32:63] = b_old[0:31], new_a[0:31] = a_old[0:31]
//   new_b[0:31]  = a_old[32:63], new_b[32:63] = b_old[32:63]
#if __has_builtin(__builtin_amdgcn_permlane32_swap)
__device__ __forceinline__ uint32x2 plswap(unsigned a, unsigned b){
    return __builtin_amdgcn_permlane32_swap(a, b, false, false);
}
#else
__device__ __forceinline__ uint32x2 plswap(unsigned a, unsigned b){
    const int hi = (threadIdx.x & 63) >> 5;
    const unsigned pa = (unsigned)__shfl_xor((int)a, 32);
    const unsigned pb = (unsigned)__shfl_xor((int)b, 32);
    uint32x2 r;
    r.x = hi ? pb : a;    // new_a
    r.y = hi ? b  : pa;   // new_b
    return r;
}
#endif

// cross-half reduce: commutative combine is convention-safe.
__device__ __forceinline__ float cross32_max(float x){
    uint32x2 r = plswap(__float_as_uint(x), __float_as_uint(x));
    return fmaxf(__uint_as_float(r.x), __uint_as_float(r.y));
}
__device__ __forceinline__ float cross32_add(float x){
    uint32x2 r = plswap(__float_as_uint(x), __float_as_uint(x));
    return __uint_as_float(r.x) + __uint_as_float(r.y);
}

__device__ __forceinline__ unsigned short f2bf(float x){
    union { float f; unsigned u; } c; c.f = x;
    unsigned r = (c.u + 0x7FFFu + ((c.u >> 16) & 1u)) >> 16;   // RNE
    return (unsigned short)r;
}

// ---------------------------------------------------------------------------
// Flat vectorized pre-pass (G13): five contiguous row-major regions, each a
// pure fp32 -> bf16 cast, processed as float4 -> ushort4 (fully coalesced).
// ---------------------------------------------------------------------------
#define XB 3072   // MTOT*H/4/256
#define WB 576    // 768*H/4/256
__global__ __launch_bounds__(256) void prep(
    const float* __restrict__ hs,
    const float* __restrict__ wq, const float* __restrict__ wk,
    const float* __restrict__ wv, const float* __restrict__ wo,
    unsigned short* __restrict__ Xh, unsigned short* __restrict__ Wqkv,
    unsigned short* __restrict__ Wo_)
{
    const int bid = blockIdx.x;
    const float* src;
    unsigned short* dst;
    int ib;
    if (bid < XB){
        src = hs; dst = Xh; ib = bid;
    } else {
        const int w = (bid - XB) / WB;
        ib = (bid - XB) - w*WB;
        src = (w==0)?wq:(w==1)?wk:(w==2)?wv:wo;
        dst = (w < 3) ? (Wqkv + (size_t)w*768*H) : Wo_;
    }
    const size_t i = (size_t)ib*256 + threadIdx.x;
    const float4 v = ((const float4*)src)[i];
    ushort4 o;
    o.x = f2bf(v.x); o.y = f2bf(v.y); o.z = f2bf(v.z); o.w = f2bf(v.w);
    ((ushort4*)dst)[i] = o;
}

// ---------------------------------------------------------------------------
// GEMM, 64x128 tile, 4 waves 2x2 (r16 form, measured best). 1-term bf16,
// K=768, BK=32, double-buffered, counted vmcnt(3) + builtin s_barrier.
// MODE 1 (QKV): Q/K stored NATURAL [b][s][H]; V scattered to V^T.
// MODE 0 (out-proj): fp32 store + bias.
// ---------------------------------------------------------------------------
template<int MODE>
__global__ __launch_bounds__(256) void gemm_bf16(
    const unsigned short* __restrict__ A, const unsigned short* __restrict__ Bm,
    const float* __restrict__ b0, const float* __restrict__ b1,
    const float* __restrict__ b2,
    float* __restrict__ out,
    unsigned short* __restrict__ Qh, unsigned short* __restrict__ Kh,
    unsigned short* __restrict__ Vh)
{
    constexpr int NIT = H/32;   // 24 K-iterations

    __shared__ unsigned short As[2][64*32];
    __shared__ unsigned short Bs[2][128*32];
    const int tid = threadIdx.x, lane = tid & 63, wave = tid >> 6;
    const int m0 = blockIdx.x*64, n0 = blockIdx.y*128;
    const int wr = wave >> 1, wc = wave & 1;
    const int frow = lane & 15, foct = lane >> 4;
    const int arow = lane >> 2;
    const int achk = ((lane & 3) ^ (arow & 3)) * 8;
    const int fswz = (foct ^ (frow & 3)) * 8;

    auto STAGE = [&](int bufi, int kp){
        {
            const int r0 = wave*16;
            GLL16(A + (size_t)(m0 + r0 + arow)*H + kp + achk, &As[bufi][r0*32]);
        }
        #pragma unroll
        for (int i = 0; i < 2; ++i){
            const int r0 = (wave*2 + i)*16;
            GLL16(Bm + (size_t)(n0 + r0 + arow)*H + kp + achk, &Bs[bufi][r0*32]);
        }
    };

    STAGE(0, 0);
    STAGE(1, 32);

    f32x4 acc[2][4] = {};

    for (int it = 0; it < NIT; ++it){
        const int cur = it & 1;
        if (it + 1 < NIT) asm volatile("s_waitcnt vmcnt(3)");
        else              asm volatile("s_waitcnt vmcnt(0)");
        SCHEDB();
        SBAR();
        SCHEDB();           // buf[cur] loads visible to all waves

        bf16x8 af[2], bfv[4];
        #pragma unroll
        for (int i = 0; i < 2; ++i)
            af[i]  = *(const bf16x8*)&As[cur][(wr*32 + 16*i + frow)*32 + fswz];
        #pragma unroll
        for (int j = 0; j < 4; ++j)
            bfv[j] = *(const bf16x8*)&Bs[cur][(wc*64 + 16*j + frow)*32 + fswz];
        #pragma unroll
        for (int i = 0; i < 2; ++i)
            #pragma unroll
            for (int j = 0; j < 4; ++j)
                acc[i][j] = MFMA16(af[i], bfv[j], acc[i][j]);

        SCHEDB();
        SBAR();             // all waves done reading buf[cur]
        SCHEDB();
        if (it + 2 < NIT) STAGE(cur, (it + 2)*32);
    }

    if (MODE == 0){
        #pragma unroll
        for (int i = 0; i < 2; ++i){
            const int m = m0 + wr*32 + 16*i + 4*foct;
            #pragma unroll
            for (int j = 0; j < 4; ++j){
                const int n = n0 + wc*64 + 16*j + frow;
                const float bb = b0[n];
                #pragma unroll
                for (int r = 0; r < 4; ++r)
                    out[(size_t)(m + r)*H + n] = acc[i][j][r] + bb;
            }
        }
    } else {
        const int sect = n0 / 768;                 // 0=Q 1=K 2=V (block-uniform)
        const float* bias = (sect==0) ? b0 : (sect==1) ? b1 : b2;
        // Q scale folds 1/sqrt(HD) AND 1/ln2 (softmax runs in exp2 space)
        const float qs = (sect==0) ? 0.125f*1.44269504f : 1.0f;
        unsigned short* Ph = (sect==0) ? Qh : Kh;
        #pragma unroll
        for (int i = 0; i < 2; ++i){
            const int m  = m0 + wr*32 + 16*i + 4*foct;
            const int bb = m >> 11, ss = m & (S_-1);
            #pragma unroll
            for (int j = 0; j < 4; ++j){
                const int nn = (n0 - sect*768) + wc*64 + 16*j + frow;
                const float bv_ = bias[nn];
                unsigned short hi[4];
                #pragma unroll
                for (int r = 0; r < 4; ++r)
                    hi[r] = f2bf((acc[i][j][r] + bv_) * qs);
                if (sect < 2){                     // NATURAL [b][s][H] (n=h*64+d)
                    #pragma unroll
                    for (int r = 0; r < 4; ++r)
                        Ph[((size_t)bb*S_ + ss + r)*H + nn] = hi[r];
                } else {                           // V^T [b][h][d][s]
                    const int hh = nn >> 6, dd = nn & 63;
                    const size_t a = ((size_t)(bb*NH + hh)*HD + dd)*S_ + ss;
                    ushort4 ph; ph.x=hi[0]; ph.y=hi[1]; ph.z=hi[2]; ph.w=hi[3];
                    *(ushort4*)&Vh[a] = ph;
                }
            }
        }
    }
}

// ---------------------------------------------------------------------------
// Flash attention, fully fused (r21 exact - measured best). Q/K read from
// NATURAL [b][s][H] layout. Grid (S/64, NH, B) = 768 blocks. Block = 64
// q-rows x all 32 k-tiles; wave-pair parity split; in-LDS merge epilogue.
// 32x32x16 MFMA swapped operands, exp2 softmax + defer-rescale, permlane
// packs, s_setprio around MFMA clusters (r22 A/B: removal cost ~2 us).
// ---------------------------------------------------------------------------
__global__ __launch_bounds__(256, 3) void attn_mfma(
    const unsigned short* __restrict__ Qh, const unsigned short* __restrict__ Kh,
    const unsigned short* __restrict__ Vh,
    const int* __restrict__ mask, unsigned short* __restrict__ Cs)
{
    __shared__ unsigned short Ksh[2][64*64];
    __shared__ unsigned short Vsh[2][64*64];

    const int tid = threadIdx.x, lane = tid & 63, wave = tid >> 6;  // 4 waves
    const int q0 = blockIdx.x*64, h = blockIdx.y, b = blockIdx.z;
    const int qb = wave & 1, kp2 = wave >> 1;     // q-block, k-parity
    const int l31 = lane & 31, hi = lane >> 5, l7 = lane & 7;
    const size_t kbase = ((size_t)b*S_)*H + h*HD; // K rows [s][H] + head slice
    const size_t vbase = (size_t)(b*NH + h)*HD;   // V rows [d][s]
    const int srow = lane >> 3;                   // 8 rows per GLL (128B slices)
    const int schk = ((lane & 7) ^ srow) * 8;     // pre-swizzled source chunk

    // stage tile te -> buf0 (K,V) and te+1 -> buf1; 8 GLLs per wave
    auto STAGE2 = [&](int te){
        if (wave == 0){
            #pragma unroll
            for (int i = 0; i < 8; ++i){
                const int r0 = i*8, row = r0 + srow;
                GLL16(Kh + kbase + (size_t)(te*64 + row)*H + schk, &Ksh[0][r0*64]);
            }
        } else if (wave == 1){
            #pragma unroll
            for (int i = 0; i < 8; ++i){
                const int r0 = i*8, row = r0 + srow;
                GLL16(Vh + (vbase + row)*S_ + (size_t)te*64 + schk, &Vsh[0][r0*64]);
            }
        } else if (wave == 2){
            #pragma unroll
            for (int i = 0; i < 8; ++i){
                const int r0 = i*8, row = r0 + srow;
                GLL16(Kh + kbase + (size_t)((te+1)*64 + row)*H + schk, &Ksh[1][r0*64]);
            }
        } else {
            #pragma unroll
            for (int i = 0; i < 8; ++i){
                const int r0 = i*8, row = r0 + srow;
                GLL16(Vh + (vbase + row)*S_ + (size_t)(te+1)*64 + schk, &Vsh[1][r0*64]);
            }
        }
    };

    // ---- mask bits: lane L holds keys L*32..L*32+31 (batch b) ----
    unsigned mbits = 0;
    {
        const int* mp = mask + (size_t)b*S_ + lane*32;
        #pragma unroll
        for (int j = 0; j < 32; ++j) mbits |= (mp[j] ? 1u : 0u) << j;
    }

    // ---- Q fragments (B-op: col=l31 -> q row q0+qb*32+l31, k=hi*8+e) ----
    bf16x8 qf[4];
    {
        const size_t qr = ((size_t)b*S_ + q0 + qb*32 + l31)*H + h*HD;
        #pragma unroll
        for (int ds = 0; ds < 4; ++ds)
            qf[ds] = *(const bf16x8*)&Qh[qr + ds*16 + hi*8];
    }

    STAGE2(0);

    float mR = -1e30f, lR = 0.f;
    f32x16 o0 = {}, o1 = {};

    for (int tt = 0; tt < 16; ++tt){
        const int t = 2*tt + kp2;                 // this wave's tile
        asm volatile("s_waitcnt vmcnt(0)");
        SCHEDB();
        SBAR();
        SCHEDB();           // both parity buffers for this round visible

        // ---- S^T = K Q'^T : 8 mfma, 2 indep chains (scores in log2 units) ----
        f32x16 s0 = {}, s1 = {};
        __builtin_amdgcn_s_setprio(1);
        #pragma unroll
        for (int ds = 0; ds < 4; ++ds){
            const int c0 = ((2*ds + hi) ^ l7)*8;
            const bf16x8 kh0 = *(const bf16x8*)&Ksh[kp2][l31*64 + c0];
            const bf16x8 kh1 = *(const bf16x8*)&Ksh[kp2][(32+l31)*64 + c0];
            s0 = MFMA32(kh0, qf[ds], s0);
            s1 = MFMA32(kh1, qf[ds], s1);
        }
        __builtin_amdgcn_s_setprio(0);

        // ---- mask via preloaded bits (no memory ops) ----
        {
            const unsigned bm_lo = (unsigned)__shfl((int)mbits, 2*t);
            const unsigned bm_hi = (unsigned)__shfl((int)mbits, 2*t + 1);
            const unsigned long long mb = ((unsigned long long)bm_hi << 32) | bm_lo;
            if (~mb){
                #pragma unroll
                for (int r = 0; r < 16; ++r){
                    const int key = (r&3) + 8*(r>>2) + 4*hi;
                    if (!((mb >> key) & 1))      s0[r] = -1e9f;
                    if (!((mb >> (key+32)) & 1)) s1[r] = -1e9f;
                }
            }
        }

        // ---- online softmax (lane-local + permlane cross-half) ----
        float vmax = -1e30f;
        #pragma unroll
        for (int r = 0; r < 16; ++r) vmax = fmaxf(vmax, fmaxf(s0[r], s1[r]));
        vmax = cross32_max(vmax);
        if (!__all(vmax <= mR + 11.5f)){          // T13 defer (log2 units)
            const float mnew = fmaxf(mR, vmax);
            const float sc = EXP2F(mR - mnew);
            mR = mnew; lR *= sc;
            #pragma unroll
            for (int r = 0; r < 16; ++r){ o0[r] *= sc; o1[r] *= sc; }
        }
        float ps = 0.f;
        #pragma unroll
        for (int r = 0; r < 16; ++r){
            s0[r] = EXP2F(s0[r] - mR);
            s1[r] = EXP2F(s1[r] - mR);
            ps += s0[r] + s1[r];
        }
        ps = cross32_add(ps);
        lR += ps;

        // ---- pack P^T to bf16 B-frags (cvt_pk + permlane32_swap builtin) ----
        bf16x8 pf[4];
        #pragma unroll
        for (int s = 0; s < 4; ++s){
            const f32x16& pv = (s < 2) ? s0 : s1;
            const int rb = (s & 1)*8;
            unsigned w0, w1, w2, w3;
            asm("v_cvt_pk_bf16_f32 %0, %1, %2" : "=v"(w0) : "v"(pv[rb+0]), "v"(pv[rb+1]));
            asm("v_cvt_pk_bf16_f32 %0, %1, %2" : "=v"(w1) : "v"(pv[rb+2]), "v"(pv[rb+3]));
            asm("v_cvt_pk_bf16_f32 %0, %1, %2" : "=v"(w2) : "v"(pv[rb+4]), "v"(pv[rb+5]));
            asm("v_cvt_pk_bf16_f32 %0, %1, %2" : "=v"(w3) : "v"(pv[rb+6]), "v"(pv[rb+7]));
            const uint32x2 r02 = plswap(w0, w2);
            const uint32x2 r13 = plswap(w1, w3);
            union { uint4 u; bf16x8 v; } pk;
            pk.u.x = r02.x; pk.u.y = r13.x; pk.u.z = r02.y; pk.u.w = r13.y;
            pf[s] = pk.v;
        }

        // ---- O^T += V^T P^T : 8 mfma, 2 indep chains ----
        __builtin_amdgcn_s_setprio(1);
        #pragma unroll
        for (int s = 0; s < 4; ++s){
            const int c0 = ((2*s + hi) ^ l7)*8;
            const bf16x8 vh0 = *(const bf16x8*)&Vsh[kp2][l31*64 + c0];
            const bf16x8 vh1 = *(const bf16x8*)&Vsh[kp2][(32+l31)*64 + c0];
            o0 = MFMA32(vh0, pf[s], o0);
            o1 = MFMA32(vh1, pf[s], o1);
        }
        __builtin_amdgcn_s_setprio(0);

        SCHEDB();
        SBAR();             // all waves done reading this round's buffers
        SCHEDB();
        if (tt + 1 < 16) STAGE2(2*(tt + 1));      // stage next parity pair
    }

    // ---- epilogue: in-LDS merge of even/odd partials, write bf16 Cs ----
    float* Olds = (float*)&Ksh[0][0];
    float* Mlds = (float*)&Vsh[0][0];
    const int qi = qb*32 + l31;

    if (kp2 == 1){          // odd-parity waves publish partials
        #pragma unroll
        for (int a = 0; a < 4; ++a){
            const int d0 = 8*a + 4*hi;
            f32x4 v0, v1;
            #pragma unroll
            for (int r = 0; r < 4; ++r){ v0[r] = o0[a*4+r]; v1[r] = o1[a*4+r]; }
            *(f32x4*)&Olds[qi*64 + d0]      = v0;
            *(f32x4*)&Olds[qi*64 + 32 + d0] = v1;
        }
        if (hi == 0){
            Mlds[qi*2]     = mR;
            Mlds[qi*2 + 1] = lR;
        }
    }
    __syncthreads();        // full drain: publishes visible to even waves

    if (kp2 == 0){          // even-parity waves merge + write
        const float mo = Mlds[qi*2], lo = Mlds[qi*2 + 1];
        const float mm = fmaxf(mR, mo);
        const float we = EXP2F(mR - mm), wo_ = EXP2F(mo - mm);
        const float inv = 1.0f / (lR*we + lo*wo_);
        const int sg = q0 + qi;
        unsigned short* Crow = Cs + ((size_t)b*S_ + sg)*H + h*HD;
        #pragma unroll
        for (int a = 0; a < 4; ++a){
            const int d0 = 8*a + 4*hi;
            ushort4 u0, u1;
            #pragma unroll
            for (int r = 0; r < 4; ++r){
                const float e0 = (o0[a*4+r]*we + Olds[qi*64 + d0 + r]*wo_)*inv;
                const float e1 = (o1[a*4+r]*we + Olds[qi*64 + 32 + d0 + r]*wo_)*inv;
                ((unsigned short*)&u0)[r] = f2bf(e0);
                ((unsigned short*)&u1)[r] = f2bf(e1);
            }
            *(ushort4*)&Crow[d0]      = u0;
            *(ushort4*)&Crow[32 + d0] = u1;
        }
    }
}

extern "C" void kernel_launch(void* const* d_in, const int* in_sizes, int n_in,
                              void* d_out, int out_size, void* d_ws, size_t ws_size,
                              hipStream_t stream) {
    const float* hs = (const float*)d_in[0];
    const int*  msk = (const int*)  d_in[1];
    const float* wq = (const float*)d_in[2];
    const float* bq = (const float*)d_in[3];
    const float* wk = (const float*)d_in[4];
    const float* bk = (const float*)d_in[5];
    const float* wv = (const float*)d_in[6];
    const float* bv = (const float*)d_in[7];
    const float* wo = (const float*)d_in[8];
    const float* bo = (const float*)d_in[9];
    float* out = (float*)d_out;

    const size_t XH_E   = (size_t)MTOT*H;        // 3.1M shorts
    const size_t WQKV_E = (size_t)2304*H;
    const size_t WO_E   = (size_t)768*H;
    const size_t QKV_E  = (size_t)MTOT*H;        // Q/K natural layout
    const size_t V_E    = (size_t)B_*NH*S_*HD;   // V^T
    const size_t CS_E   = (size_t)MTOT*H;        // 3.1M shorts

    unsigned short* p = (unsigned short*)d_ws;
    unsigned short* Xh   = p; p += XH_E;
    unsigned short* Wqkv = p; p += WQKV_E;
    unsigned short* Wo_  = p; p += WO_E;
    unsigned short* Qh = p; p += QKV_E;
    unsigned short* Kh = p; p += QKV_E;
    unsigned short* Vh = p; p += V_E;
    unsigned short* Cs = p; p += CS_E;

    prep<<<dim3(XB + 4*WB), 256, 0, stream>>>(
        hs, wq, wk, wv, wo, Xh, Wqkv, Wo_);
    gemm_bf16<1><<<dim3(MTOT/64, 2304/128), 256, 0, stream>>>(
        Xh, Wqkv, bq, bk, bv, nullptr, Qh, Kh, Vh);
    attn_mfma<<<dim3(S_/64, NH, B_), 256, 0, stream>>>(
        Qh, Kh, Vh, msk, Cs);
    gemm_bf16<0><<<dim3(MTOT/64, H/128), 256, 0, stream>>>(
        Cs, Wo_, bo, nullptr, nullptr, out,
        nullptr, nullptr, nullptr);
}